// Round 1
// baseline (1455.021 us; speedup 1.0000x reference)
//
#include <hip/hip_runtime.h>
#include <hip/hip_bf16.h>

#define N_NODES 50000
#define N_EDGES 1600000
#define N_GRAPHS 64

// ---------- helpers ----------
__device__ __forceinline__ unsigned fenc(float x) {
    unsigned u = __float_as_uint(x);
    return (u & 0x80000000u) ? ~u : (u | 0x80000000u);
}
__device__ __forceinline__ float fdec(unsigned e) {
    return (e & 0x80000000u) ? __uint_as_float(e & 0x7fffffffu) : __uint_as_float(~e);
}

// ---------- GEMM: Y[nrows,OUT] = X[nrows,IN] @ W[IN,OUT] (W cached in LDS) ----------
template<int IN, int OUT>
__global__ void gemm_rows(const float* __restrict__ X, const float* __restrict__ W,
                          float* __restrict__ Y, int nrows) {
    constexpr int NPB = 256 / OUT;                 // nodes per block-iteration
    __shared__ float Wl[IN * OUT];
    __shared__ float Xl[NPB * IN];
    for (int i = threadIdx.x; i < IN * OUT; i += 256) Wl[i] = W[i];
    __syncthreads();
    const int lane_out = threadIdx.x % OUT;
    const int lrow     = threadIdx.x / OUT;
    for (int base = blockIdx.x * NPB; base < nrows; base += gridDim.x * NPB) {
        for (int i = threadIdx.x; i < NPB * IN; i += 256) {
            int r = base + i / IN;
            Xl[i] = (r < nrows) ? X[(size_t)r * IN + (i % IN)] : 0.f;
        }
        __syncthreads();
        int r = base + lrow;
        if (r < nrows) {
            float acc = 0.f;
            #pragma unroll 8
            for (int k = 0; k < IN; ++k)
                acc += Xl[lrow * IN + k] * Wl[k * OUT + lane_out];
            Y[(size_t)r * OUT + lane_out] = acc;
        }
        __syncthreads();
    }
}

// ---------- degree: deg[dst] += ew ----------
__global__ void deg_kernel(const int* __restrict__ dst, const float* __restrict__ ew,
                           float* __restrict__ deg) {
    int e = blockIdx.x * 256 + threadIdx.x;
    if (e < N_EDGES) atomicAdd(&deg[dst[e]], ew[e]);
}

__global__ void dinv_kernel(float* __restrict__ deg_inplace) {
    int n = blockIdx.x * 256 + threadIdx.x;
    if (n < N_NODES) deg_inplace[n] = rsqrtf(deg_inplace[n] + 1.0f);
}

__global__ void coef_kernel(const int* __restrict__ src, const int* __restrict__ dst,
                            const float* __restrict__ ew, const float* __restrict__ dinv,
                            float* __restrict__ coef) {
    int e = blockIdx.x * 256 + threadIdx.x;
    if (e < N_EDGES) coef[e] = dinv[src[e]] * ew[e] * dinv[dst[e]];
}

// ---------- edge scatter: agg[dst] += coef * xw[src] ----------
template<int OUT>
__global__ void scatter_kernel(const int* __restrict__ src, const int* __restrict__ dst,
                               const float* __restrict__ coef, const float* __restrict__ xw,
                               float* __restrict__ agg) {
    constexpr int EPB = 256 / OUT;
    const int k  = threadIdx.x % OUT;
    const int le = threadIdx.x / OUT;
    long e = (long)blockIdx.x * EPB + le;
    if (e < N_EDGES) {
        int s = src[e], d = dst[e];
        float c = coef[e];
        atomicAdd(&agg[(size_t)d * OUT + k], c * xw[(size_t)s * OUT + k]);
    }
}

// ---------- self-loop + bias + relu (in place on agg) ----------
template<int OUT>
__global__ void selfloop_relu(const float* __restrict__ xw, const float* __restrict__ dinv,
                              const float* __restrict__ b, float* __restrict__ agg) {
    size_t i = (size_t)blockIdx.x * 256 + threadIdx.x;
    if (i >= (size_t)N_NODES * OUT) return;
    int n = (int)(i / OUT), k = (int)(i % OUT);
    float di = dinv[n];
    float v = agg[i] + di * di * xw[i] + b[k];
    agg[i] = fmaxf(v, 0.f);
}

// ---------- gate: g[n] = relu(x1@gW1+gb1)@gW2+gb2; wave-reduced segment max ----------
__global__ void gate_kernel(const float* __restrict__ x1, const float* __restrict__ gW1,
                            const float* __restrict__ gb1, const float* __restrict__ gW2,
                            const float* __restrict__ gb2, const int* __restrict__ batch,
                            float* __restrict__ g, unsigned* __restrict__ gmax_enc) {
    __shared__ float W1l[64 * 32];
    __shared__ float W2l[32];
    __shared__ float b1l[32];
    for (int i = threadIdx.x; i < 64 * 32; i += 256) W1l[i] = gW1[i];
    if (threadIdx.x < 32) { W2l[threadIdx.x] = gW2[threadIdx.x]; b1l[threadIdx.x] = gb1[threadIdx.x]; }
    __syncthreads();
    const float gb2v = gb2[0];
    int n = blockIdx.x * 256 + threadIdx.x;
    bool act = (n < N_NODES);
    float gv = -1e30f;
    int b = 0;
    if (act) {
        const float* row = x1 + (size_t)n * 64;
        float t[32];
        #pragma unroll
        for (int j = 0; j < 32; ++j) t[j] = b1l[j];
        for (int k = 0; k < 64; ++k) {
            float xv = row[k];
            #pragma unroll
            for (int j = 0; j < 32; ++j) t[j] += xv * W1l[k * 32 + j];
        }
        float a = gb2v;
        #pragma unroll
        for (int j = 0; j < 32; ++j) a += fmaxf(t[j], 0.f) * W2l[j];
        gv = a;
        g[n] = a;
        b = batch[n];
    }
    // wave-level max reduction when the whole wave is one graph (batch is sorted)
    unsigned long long actm = __ballot(act);
    int b0 = __shfl(b, 0);
    bool uniform = (actm == ~0ull) && (__ballot(b == b0) == ~0ull);
    if (uniform) {
        float m = gv;
        for (int o = 32; o; o >>= 1) m = fmaxf(m, __shfl_xor(m, o));
        if ((threadIdx.x & 63) == 0) atomicMax(&gmax_enc[b0], fenc(m));
    } else if (act) {
        atomicMax(&gmax_enc[b], fenc(gv));
    }
}

// ---------- ex = exp(g - gmax[batch]); den[batch] += ex (wave-reduced) ----------
__global__ void exp_kernel(const float* __restrict__ g, const int* __restrict__ batch,
                           const unsigned* __restrict__ gmax_enc, float* __restrict__ ex,
                           float* __restrict__ den) {
    int n = blockIdx.x * 256 + threadIdx.x;
    bool act = (n < N_NODES);
    float v = 0.f; int b = 0;
    if (act) {
        b = batch[n];
        v = expf(g[n] - fdec(gmax_enc[b]));
        ex[n] = v;
    }
    unsigned long long actm = __ballot(act);
    int b0 = __shfl(b, 0);
    bool uniform = (actm == ~0ull) && (__ballot(b == b0) == ~0ull);
    if (uniform) {
        float s = v;
        for (int o = 32; o; o >>= 1) s += __shfl_xor(s, o);
        if ((threadIdx.x & 63) == 0) atomicAdd(&den[b0], s);
    } else if (act) {
        atomicAdd(&den[b], v);
    }
}

__global__ void alpha_kernel(float* __restrict__ ex, const int* __restrict__ batch,
                             const float* __restrict__ den) {
    int n = blockIdx.x * 256 + threadIdx.x;
    if (n < N_NODES) ex[n] = ex[n] / den[batch[n]];
}

// ---------- pooled[batch] += alpha * x1 (run-length accumulate, batch sorted) ----------
__global__ void pool_kernel(const float* __restrict__ x1, const float* __restrict__ alpha,
                            const int* __restrict__ batch, float* __restrict__ pooled) {
    const int L = 32;                           // nodes per chunk
    const int f   = threadIdx.x & 63;
    const int grp = threadIdx.x >> 6;
    int chunk = blockIdx.x * 4 + grp;
    int start = chunk * L;
    if (start >= N_NODES) return;
    int end = min(start + L, N_NODES);
    int cur = batch[start];
    float acc = 0.f;
    for (int n = start; n < end; ++n) {
        int bb = batch[n];
        if (bb != cur) { atomicAdd(&pooled[cur * 64 + f], acc); acc = 0.f; cur = bb; }
        acc += alpha[n] * x1[(size_t)n * 64 + f];
    }
    atomicAdd(&pooled[cur * 64 + f], acc);
}

// ---------- head: h2 = relu(pooled@fcW1+fcb1); logits = h2@fcW2+fcb2; log_softmax ----------
__global__ void head_kernel(const float* __restrict__ pooled, const float* __restrict__ fcW1,
                            const float* __restrict__ fcb1, const float* __restrict__ fcW2,
                            const float* __restrict__ fcb2, float* __restrict__ out) {
    __shared__ float P[64 * 64];
    __shared__ float W1l[64 * 128];
    __shared__ float H[64 * 128];
    for (int i = threadIdx.x; i < 64 * 64; i += 256) P[i] = pooled[i];
    for (int i = threadIdx.x; i < 64 * 128; i += 256) W1l[i] = fcW1[i];
    __syncthreads();
    for (int i = threadIdx.x; i < 64 * 128; i += 256) {
        int gi = i >> 7, j = i & 127;
        float a = fcb1[j];
        for (int k = 0; k < 64; ++k) a += P[gi * 64 + k] * W1l[k * 128 + j];
        H[i] = fmaxf(a, 0.f);
    }
    __syncthreads();
    if (threadIdx.x < 64) {
        int gi = threadIdx.x;
        float l0 = fcb2[0], l1 = fcb2[1];
        for (int k = 0; k < 128; ++k) {
            float h = H[gi * 128 + k];
            l0 += h * fcW2[k * 2 + 0];
            l1 += h * fcW2[k * 2 + 1];
        }
        float m = fmaxf(l0, l1);
        float lse = m + logf(expf(l0 - m) + expf(l1 - m));
        out[gi * 2 + 0] = l0 - lse;
        out[gi * 2 + 1] = l1 - lse;
    }
}

extern "C" void kernel_launch(void* const* d_in, const int* in_sizes, int n_in,
                              void* d_out, int out_size, void* d_ws, size_t ws_size,
                              hipStream_t stream) {
    const float* x    = (const float*)d_in[0];
    const int*   ei   = (const int*)d_in[1];
    const float* ew   = (const float*)d_in[2];
    const int*   batch= (const int*)d_in[3];
    const float* W1   = (const float*)d_in[4];
    const float* b1   = (const float*)d_in[5];
    const float* W2   = (const float*)d_in[6];
    const float* b2   = (const float*)d_in[7];
    const float* gW1  = (const float*)d_in[8];
    const float* gb1  = (const float*)d_in[9];
    const float* gW2  = (const float*)d_in[10];
    const float* gb2  = (const float*)d_in[11];
    const float* fcW1 = (const float*)d_in[12];
    const float* fcb1 = (const float*)d_in[13];
    const float* fcW2 = (const float*)d_in[14];
    const float* fcb2 = (const float*)d_in[15];
    float* out = (float*)d_out;

    const int* src = ei;
    const int* dst = ei + N_EDGES;

    // workspace layout (floats)
    float* ws = (float*)d_ws;
    float* xw    = ws;                       // 6,400,000  (xw1 [N,128] then xw2 [N,64])
    float* agg   = ws + 6400000;             // 6,400,000  (agg1/h then agg2/x1)
    float* coef  = ws + 12800000;            // 1,600,000
    float* dinv  = ws + 14400000;            // 50,000   (deg -> dinv in place)
    float* g     = ws + 14450000;            // 50,000
    float* ex    = ws + 14500000;            // 50,000   (ex -> alpha in place)
    unsigned* gmax = (unsigned*)(ws + 14550000); // 64
    float* den   = ws + 14550064;            // 64
    float* pooled= ws + 14550128;            // 4,096

    const int EB = (N_EDGES + 255) / 256;    // 6250
    const int NB = (N_NODES + 255) / 256;    // 196

    // degree / norm (shared by both convs)
    hipMemsetAsync(dinv, 0, N_NODES * sizeof(float), stream);
    deg_kernel<<<EB, 256, 0, stream>>>(dst, ew, dinv);
    dinv_kernel<<<NB, 256, 0, stream>>>(dinv);
    coef_kernel<<<EB, 256, 0, stream>>>(src, dst, ew, dinv, coef);

    // conv1: xw1 = x@W1; agg1 = scatter + selfloop + b1, relu -> h (in agg)
    gemm_rows<128, 128><<<2048, 256, 0, stream>>>(x, W1, xw, N_NODES);
    hipMemsetAsync(agg, 0, (size_t)N_NODES * 128 * sizeof(float), stream);
    scatter_kernel<128><<<(N_EDGES * 128 + 255) / 256, 256, 0, stream>>>(src, dst, coef, xw, agg);
    selfloop_relu<128><<<((size_t)N_NODES * 128 + 255) / 256, 256, 0, stream>>>(xw, dinv, b1, agg);

    // conv2: xw2 = h@W2; agg2 = scatter + selfloop + b2, relu -> x1 (in agg)
    gemm_rows<128, 64><<<2048, 256, 0, stream>>>(agg, W2, xw, N_NODES);
    hipMemsetAsync(agg, 0, (size_t)N_NODES * 64 * sizeof(float), stream);
    scatter_kernel<64><<<(N_EDGES * 64 + 255) / 256, 256, 0, stream>>>(src, dst, coef, xw, agg);
    selfloop_relu<64><<<((size_t)N_NODES * 64 + 255) / 256, 256, 0, stream>>>(xw, dinv, b2, agg);

    // global attention
    hipMemsetAsync(gmax, 0, N_GRAPHS * sizeof(unsigned), stream);   // enc(0)=smallest
    hipMemsetAsync(den, 0, N_GRAPHS * sizeof(float), stream);
    hipMemsetAsync(pooled, 0, N_GRAPHS * 64 * sizeof(float), stream);
    gate_kernel<<<NB, 256, 0, stream>>>(agg, gW1, gb1, gW2, gb2, batch, g, gmax);
    exp_kernel<<<NB, 256, 0, stream>>>(g, batch, gmax, ex, den);
    alpha_kernel<<<NB, 256, 0, stream>>>(ex, batch, den);
    {
        int nchunks = (N_NODES + 31) / 32;
        pool_kernel<<<(nchunks + 3) / 4, 256, 0, stream>>>(agg, ex, batch, pooled);
    }

    // head
    head_kernel<<<1, 256, 0, stream>>>(pooled, fcW1, fcb1, fcW2, fcb2, out);
}

// Round 2
// 850.760 us; speedup vs baseline: 1.7103x; 1.7103x over previous
//
#include <hip/hip_runtime.h>
#include <hip/hip_bf16.h>

#define N_NODES 50000
#define N_EDGES 1600000
#define N_GRAPHS 64

// ---------- helpers ----------
__device__ __forceinline__ unsigned fenc(float x) {
    unsigned u = __float_as_uint(x);
    return (u & 0x80000000u) ? ~u : (u | 0x80000000u);
}
__device__ __forceinline__ float fdec(unsigned e) {
    return (e & 0x80000000u) ? __uint_as_float(e & 0x7fffffffu) : __uint_as_float(~e);
}

// ---------- GEMM: Y[nrows,OUT] = X[nrows,IN] @ W[IN,OUT] (W cached in LDS) ----------
template<int IN, int OUT>
__global__ void gemm_rows(const float* __restrict__ X, const float* __restrict__ W,
                          float* __restrict__ Y, int nrows) {
    constexpr int NPB = 256 / OUT;                 // nodes per block-iteration
    __shared__ float Wl[IN * OUT];
    __shared__ float Xl[NPB * IN];
    for (int i = threadIdx.x; i < IN * OUT; i += 256) Wl[i] = W[i];
    __syncthreads();
    const int lane_out = threadIdx.x % OUT;
    const int lrow     = threadIdx.x / OUT;
    for (int base = blockIdx.x * NPB; base < nrows; base += gridDim.x * NPB) {
        for (int i = threadIdx.x; i < NPB * IN; i += 256) {
            int r = base + i / IN;
            Xl[i] = (r < nrows) ? X[(size_t)r * IN + (i % IN)] : 0.f;
        }
        __syncthreads();
        int r = base + lrow;
        if (r < nrows) {
            float acc = 0.f;
            #pragma unroll 8
            for (int k = 0; k < IN; ++k)
                acc += Xl[lrow * IN + k] * Wl[k * OUT + lane_out];
            Y[(size_t)r * OUT + lane_out] = acc;
        }
        __syncthreads();
    }
}

// ---------- histogram: deg[dst] += ew (float), cnt[dst] += 1 (int) ----------
__global__ void hist_kernel(const int* __restrict__ dst, const float* __restrict__ ew,
                            float* __restrict__ deg, int* __restrict__ cnt) {
    int e = blockIdx.x * 256 + threadIdx.x;
    if (e < N_EDGES) {
        int d = dst[e];
        atomicAdd(&deg[d], ew[e]);
        atomicAdd(&cnt[d], 1);
    }
}

__global__ void dinv_kernel(float* __restrict__ deg_inplace) {
    int n = blockIdx.x * 256 + threadIdx.x;
    if (n < N_NODES) deg_inplace[n] = rsqrtf(deg_inplace[n] + 1.0f);
}

// ---------- prefix-scan (hierarchical, 3 kernels) ----------
__global__ void block_sums(const int* __restrict__ cnt, int* __restrict__ bsum) {
    __shared__ int s[256];
    int idx = blockIdx.x * 256 + threadIdx.x;
    s[threadIdx.x] = (idx < N_NODES) ? cnt[idx] : 0;
    __syncthreads();
    for (int o = 128; o; o >>= 1) {
        if (threadIdx.x < o) s[threadIdx.x] += s[threadIdx.x + o];
        __syncthreads();
    }
    if (threadIdx.x == 0) bsum[blockIdx.x] = s[0];
}

__global__ void scan_bsums(const int* __restrict__ bsum, int* __restrict__ boff,
                           int nb, int* __restrict__ row_start_last) {
    __shared__ int s[256];
    int v = (threadIdx.x < nb) ? bsum[threadIdx.x] : 0;
    s[threadIdx.x] = v;
    __syncthreads();
    for (int o = 1; o < 256; o <<= 1) {
        int t = 0;
        if (threadIdx.x >= o) t = s[threadIdx.x - o];
        __syncthreads();
        s[threadIdx.x] += t;
        __syncthreads();
    }
    if (threadIdx.x < nb) boff[threadIdx.x] = s[threadIdx.x] - v;   // exclusive
    if (threadIdx.x == 0) *row_start_last = N_EDGES;
}

__global__ void scan_counts(const int* __restrict__ cnt, const int* __restrict__ boff,
                            int* __restrict__ row_start, int* __restrict__ cursor) {
    __shared__ int s[256];
    int idx = blockIdx.x * 256 + threadIdx.x;
    int v = (idx < N_NODES) ? cnt[idx] : 0;
    s[threadIdx.x] = v;
    __syncthreads();
    for (int o = 1; o < 256; o <<= 1) {
        int t = 0;
        if (threadIdx.x >= o) t = s[threadIdx.x - o];
        __syncthreads();
        s[threadIdx.x] += t;
        __syncthreads();
    }
    if (idx < N_NODES) {
        int ex = boff[blockIdx.x] + s[threadIdx.x] - v;   // exclusive scan
        row_start[idx] = ex;
        cursor[idx]    = ex;
    }
}

// ---------- fill CSR: csr_src/csr_coef sorted by dst ----------
__global__ void fill_csr(const int* __restrict__ src, const int* __restrict__ dst,
                         const float* __restrict__ ew, const float* __restrict__ dinv,
                         int* __restrict__ cursor,
                         int* __restrict__ csr_src, float* __restrict__ csr_coef) {
    int e = blockIdx.x * 256 + threadIdx.x;
    if (e < N_EDGES) {
        int s = src[e], d = dst[e];
        float c = dinv[s] * ew[e] * dinv[d];
        int pos = atomicAdd(&cursor[d], 1);
        csr_src[pos]  = s;
        csr_coef[pos] = c;
    }
}

// ---------- CSR aggregation + self-loop + bias + relu, fused ----------
template<int OUT>
__global__ void agg_csr(const int* __restrict__ row_start, const int* __restrict__ csr_src,
                        const float* __restrict__ csr_coef, const float* __restrict__ xw,
                        const float* __restrict__ dinv, const float* __restrict__ b,
                        float* __restrict__ out_h) {
    constexpr int NPB = 256 / OUT;              // nodes per block
    const int n = blockIdx.x * NPB + threadIdx.x / OUT;
    const int k = threadIdx.x % OUT;
    if (n >= N_NODES) return;
    const int beg = row_start[n], end = row_start[n + 1];
    float acc = 0.f;
    int i = beg;
    for (; i + 1 < end; i += 2) {
        int s0 = csr_src[i], s1 = csr_src[i + 1];
        float c0 = csr_coef[i], c1 = csr_coef[i + 1];
        float v0 = xw[(size_t)s0 * OUT + k];
        float v1 = xw[(size_t)s1 * OUT + k];
        acc += c0 * v0 + c1 * v1;
    }
    if (i < end) acc += csr_coef[i] * xw[(size_t)csr_src[i] * OUT + k];
    float di = dinv[n];
    float v = acc + di * di * xw[(size_t)n * OUT + k] + b[k];
    out_h[(size_t)n * OUT + k] = fmaxf(v, 0.f);
}

// ---------- fallback: atomic scatter path (if ws too small) ----------
__global__ void coef_kernel(const int* __restrict__ src, const int* __restrict__ dst,
                            const float* __restrict__ ew, const float* __restrict__ dinv,
                            float* __restrict__ coef) {
    int e = blockIdx.x * 256 + threadIdx.x;
    if (e < N_EDGES) coef[e] = dinv[src[e]] * ew[e] * dinv[dst[e]];
}

template<int OUT>
__global__ void scatter_kernel(const int* __restrict__ src, const int* __restrict__ dst,
                               const float* __restrict__ coef, const float* __restrict__ xw,
                               float* __restrict__ agg) {
    constexpr int EPB = 256 / OUT;
    const int k  = threadIdx.x % OUT;
    const int le = threadIdx.x / OUT;
    long e = (long)blockIdx.x * EPB + le;
    if (e < N_EDGES) {
        int s = src[e], d = dst[e];
        atomicAdd(&agg[(size_t)d * OUT + k], coef[e] * xw[(size_t)s * OUT + k]);
    }
}

template<int OUT>
__global__ void selfloop_relu(const float* __restrict__ xw, const float* __restrict__ dinv,
                              const float* __restrict__ b, float* __restrict__ agg) {
    size_t i = (size_t)blockIdx.x * 256 + threadIdx.x;
    if (i >= (size_t)N_NODES * OUT) return;
    int n = (int)(i / OUT), k = (int)(i % OUT);
    float di = dinv[n];
    float v = agg[i] + di * di * xw[i] + b[k];
    agg[i] = fmaxf(v, 0.f);
}

// ---------- gate: g[n] = relu(x1@gW1+gb1)@gW2+gb2; wave-reduced segment max ----------
__global__ void gate_kernel(const float* __restrict__ x1, const float* __restrict__ gW1,
                            const float* __restrict__ gb1, const float* __restrict__ gW2,
                            const float* __restrict__ gb2, const int* __restrict__ batch,
                            float* __restrict__ g, unsigned* __restrict__ gmax_enc) {
    __shared__ float W1l[64 * 32];
    __shared__ float W2l[32];
    __shared__ float b1l[32];
    for (int i = threadIdx.x; i < 64 * 32; i += 256) W1l[i] = gW1[i];
    if (threadIdx.x < 32) { W2l[threadIdx.x] = gW2[threadIdx.x]; b1l[threadIdx.x] = gb1[threadIdx.x]; }
    __syncthreads();
    const float gb2v = gb2[0];
    int n = blockIdx.x * 256 + threadIdx.x;
    bool act = (n < N_NODES);
    float gv = -1e30f;
    int b = 0;
    if (act) {
        const float* row = x1 + (size_t)n * 64;
        float t[32];
        #pragma unroll
        for (int j = 0; j < 32; ++j) t[j] = b1l[j];
        for (int k = 0; k < 64; ++k) {
            float xv = row[k];
            #pragma unroll
            for (int j = 0; j < 32; ++j) t[j] += xv * W1l[k * 32 + j];
        }
        float a = gb2v;
        #pragma unroll
        for (int j = 0; j < 32; ++j) a += fmaxf(t[j], 0.f) * W2l[j];
        gv = a;
        g[n] = a;
        b = batch[n];
    }
    unsigned long long actm = __ballot(act);
    int b0 = __shfl(b, 0);
    bool uniform = (actm == ~0ull) && (__ballot(b == b0) == ~0ull);
    if (uniform) {
        float m = gv;
        for (int o = 32; o; o >>= 1) m = fmaxf(m, __shfl_xor(m, o));
        if ((threadIdx.x & 63) == 0) atomicMax(&gmax_enc[b0], fenc(m));
    } else if (act) {
        atomicMax(&gmax_enc[b], fenc(gv));
    }
}

__global__ void exp_kernel(const float* __restrict__ g, const int* __restrict__ batch,
                           const unsigned* __restrict__ gmax_enc, float* __restrict__ ex,
                           float* __restrict__ den) {
    int n = blockIdx.x * 256 + threadIdx.x;
    bool act = (n < N_NODES);
    float v = 0.f; int b = 0;
    if (act) {
        b = batch[n];
        v = expf(g[n] - fdec(gmax_enc[b]));
        ex[n] = v;
    }
    unsigned long long actm = __ballot(act);
    int b0 = __shfl(b, 0);
    bool uniform = (actm == ~0ull) && (__ballot(b == b0) == ~0ull);
    if (uniform) {
        float s = v;
        for (int o = 32; o; o >>= 1) s += __shfl_xor(s, o);
        if ((threadIdx.x & 63) == 0) atomicAdd(&den[b0], s);
    } else if (act) {
        atomicAdd(&den[b], v);
    }
}

__global__ void alpha_kernel(float* __restrict__ ex, const int* __restrict__ batch,
                             const float* __restrict__ den) {
    int n = blockIdx.x * 256 + threadIdx.x;
    if (n < N_NODES) ex[n] = ex[n] / den[batch[n]];
}

// ---------- pooled[batch] += alpha * x1 (run-length accumulate, batch sorted) ----------
__global__ void pool_kernel(const float* __restrict__ x1, const float* __restrict__ alpha,
                            const int* __restrict__ batch, float* __restrict__ pooled) {
    const int L = 32;
    const int f   = threadIdx.x & 63;
    const int grp = threadIdx.x >> 6;
    int chunk = blockIdx.x * 4 + grp;
    int start = chunk * L;
    if (start >= N_NODES) return;
    int end = min(start + L, N_NODES);
    int cur = batch[start];
    float acc = 0.f;
    for (int n = start; n < end; ++n) {
        int bb = batch[n];
        if (bb != cur) { atomicAdd(&pooled[cur * 64 + f], acc); acc = 0.f; cur = bb; }
        acc += alpha[n] * x1[(size_t)n * 64 + f];
    }
    atomicAdd(&pooled[cur * 64 + f], acc);
}

// ---------- head ----------
__global__ void head_kernel(const float* __restrict__ pooled, const float* __restrict__ fcW1,
                            const float* __restrict__ fcb1, const float* __restrict__ fcW2,
                            const float* __restrict__ fcb2, float* __restrict__ out) {
    __shared__ float P[64 * 64];
    __shared__ float W1l[64 * 128];
    __shared__ float H[64 * 128];
    for (int i = threadIdx.x; i < 64 * 64; i += 256) P[i] = pooled[i];
    for (int i = threadIdx.x; i < 64 * 128; i += 256) W1l[i] = fcW1[i];
    __syncthreads();
    for (int i = threadIdx.x; i < 64 * 128; i += 256) {
        int gi = i >> 7, j = i & 127;
        float a = fcb1[j];
        for (int k = 0; k < 64; ++k) a += P[gi * 64 + k] * W1l[k * 128 + j];
        H[i] = fmaxf(a, 0.f);
    }
    __syncthreads();
    if (threadIdx.x < 64) {
        int gi = threadIdx.x;
        float l0 = fcb2[0], l1 = fcb2[1];
        for (int k = 0; k < 128; ++k) {
            float h = H[gi * 128 + k];
            l0 += h * fcW2[k * 2 + 0];
            l1 += h * fcW2[k * 2 + 1];
        }
        float m = fmaxf(l0, l1);
        float lse = m + logf(expf(l0 - m) + expf(l1 - m));
        out[gi * 2 + 0] = l0 - lse;
        out[gi * 2 + 1] = l1 - lse;
    }
}

extern "C" void kernel_launch(void* const* d_in, const int* in_sizes, int n_in,
                              void* d_out, int out_size, void* d_ws, size_t ws_size,
                              hipStream_t stream) {
    const float* x    = (const float*)d_in[0];
    const int*   ei   = (const int*)d_in[1];
    const float* ew   = (const float*)d_in[2];
    const int*   batch= (const int*)d_in[3];
    const float* W1   = (const float*)d_in[4];
    const float* b1   = (const float*)d_in[5];
    const float* W2   = (const float*)d_in[6];
    const float* b2   = (const float*)d_in[7];
    const float* gW1  = (const float*)d_in[8];
    const float* gb1  = (const float*)d_in[9];
    const float* gW2  = (const float*)d_in[10];
    const float* gb2  = (const float*)d_in[11];
    const float* fcW1 = (const float*)d_in[12];
    const float* fcb1 = (const float*)d_in[13];
    const float* fcW2 = (const float*)d_in[14];
    const float* fcb2 = (const float*)d_in[15];
    float* out = (float*)d_out;

    const int* src = ei;
    const int* dst = ei + N_EDGES;

    const int EB = (N_EDGES + 255) / 256;    // 6250
    const int NB = (N_NODES + 255) / 256;    // 196

    // ---- workspace layout (floats) ----
    // big buffers
    float* ws = (float*)d_ws;
    float* xw    = ws;                        // 6,400,000
    float* agg   = ws + 6400000;              // 6,400,000
    size_t off = 12800000;

    // CSR-path sizing: + csr_src + csr_coef + row_start + cnt + cursor + small
    const size_t CSR_NEED_FLOATS = 12800000ull + 1600000 + 1600000
                                 + 50048 /*row_start*/ + 50048 /*cnt*/ + 50048 /*cursor*/
                                 + 50048 /*dinv*/ + 50048 /*g*/ + 50048 /*ex*/
                                 + 512 /*bsum+boff*/ + 64 + 64 + 4096;
    bool use_csr = ws_size >= CSR_NEED_FLOATS * sizeof(float);

    if (use_csr) {
        int*   csr_src  = (int*)(ws + off);   off += 1600000;
        float* csr_coef = ws + off;           off += 1600000;
        int*   row_start= (int*)(ws + off);   off += 50048;
        int*   cnt      = (int*)(ws + off);   off += 50048;
        int*   cursor   = (int*)(ws + off);   off += 50048;
        float* dinv     = ws + off;           off += 50048;
        float* g        = ws + off;           off += 50048;
        float* ex       = ws + off;           off += 50048;
        int*   bsum     = (int*)(ws + off);   off += 256;
        int*   boff     = (int*)(ws + off);   off += 256;
        unsigned* gmax  = (unsigned*)(ws + off); off += 64;
        float* den      = ws + off;           off += 64;
        float* pooled   = ws + off;           off += 4096;

        // degrees + counts
        hipMemsetAsync(dinv, 0, N_NODES * sizeof(float), stream);
        hipMemsetAsync(cnt, 0, N_NODES * sizeof(int), stream);
        hist_kernel<<<EB, 256, 0, stream>>>(dst, ew, dinv, cnt);
        dinv_kernel<<<NB, 256, 0, stream>>>(dinv);

        // prefix scan -> row_start, cursor
        block_sums<<<NB, 256, 0, stream>>>(cnt, bsum);
        scan_bsums<<<1, 256, 0, stream>>>(bsum, boff, NB, row_start + N_NODES);
        scan_counts<<<NB, 256, 0, stream>>>(cnt, boff, row_start, cursor);

        // fill CSR (coef computed inline)
        fill_csr<<<EB, 256, 0, stream>>>(src, dst, ew, dinv, cursor, csr_src, csr_coef);

        // conv1
        gemm_rows<128, 128><<<2048, 256, 0, stream>>>(x, W1, xw, N_NODES);
        agg_csr<128><<<(N_NODES + 1) / 2, 256, 0, stream>>>(row_start, csr_src, csr_coef,
                                                            xw, dinv, b1, agg);
        // conv2
        gemm_rows<128, 64><<<2048, 256, 0, stream>>>(agg, W2, xw, N_NODES);
        agg_csr<64><<<(N_NODES + 3) / 4, 256, 0, stream>>>(row_start, csr_src, csr_coef,
                                                           xw, dinv, b2, agg);

        // global attention
        hipMemsetAsync(gmax, 0, N_GRAPHS * sizeof(unsigned), stream);
        hipMemsetAsync(den, 0, N_GRAPHS * sizeof(float), stream);
        hipMemsetAsync(pooled, 0, N_GRAPHS * 64 * sizeof(float), stream);
        gate_kernel<<<NB, 256, 0, stream>>>(agg, gW1, gb1, gW2, gb2, batch, g, gmax);
        exp_kernel<<<NB, 256, 0, stream>>>(g, batch, gmax, ex, den);
        alpha_kernel<<<NB, 256, 0, stream>>>(ex, batch, den);
        int nchunks = (N_NODES + 31) / 32;
        pool_kernel<<<(nchunks + 3) / 4, 256, 0, stream>>>(agg, ex, batch, pooled);

        head_kernel<<<1, 256, 0, stream>>>(pooled, fcW1, fcb1, fcW2, fcb2, out);
    } else {
        // fallback: round-1 atomic-scatter path (ws-lean)
        float* coef  = ws + off;              off += 1600000;
        float* dinv  = ws + off;              off += 50048;
        float* g     = ws + off;              off += 50048;
        float* ex    = ws + off;              off += 50048;
        unsigned* gmax = (unsigned*)(ws + off); off += 64;
        float* den   = ws + off;              off += 64;
        float* pooled= ws + off;              off += 4096;
        int* cnt_dummy = (int*)(ws + off);    // reuse g region safe? no: allocate after
        // (cnt for hist unused in fallback: use coef region pre-coef as scratch)
        hipMemsetAsync(dinv, 0, N_NODES * sizeof(float), stream);
        hipMemsetAsync((void*)coef, 0, N_NODES * sizeof(int), stream); // temp cnt in coef buf
        hist_kernel<<<EB, 256, 0, stream>>>(dst, ew, dinv, (int*)coef);
        dinv_kernel<<<NB, 256, 0, stream>>>(dinv);
        coef_kernel<<<EB, 256, 0, stream>>>(src, dst, ew, dinv, coef);

        gemm_rows<128, 128><<<2048, 256, 0, stream>>>(x, W1, xw, N_NODES);
        hipMemsetAsync(agg, 0, (size_t)N_NODES * 128 * sizeof(float), stream);
        scatter_kernel<128><<<(N_EDGES * 128 + 255) / 256, 256, 0, stream>>>(src, dst, coef, xw, agg);
        selfloop_relu<128><<<((size_t)N_NODES * 128 + 255) / 256, 256, 0, stream>>>(xw, dinv, b1, agg);

        gemm_rows<128, 64><<<2048, 256, 0, stream>>>(agg, W2, xw, N_NODES);
        hipMemsetAsync(agg, 0, (size_t)N_NODES * 64 * sizeof(float), stream);
        scatter_kernel<64><<<(N_EDGES * 64 + 255) / 256, 256, 0, stream>>>(src, dst, coef, xw, agg);
        selfloop_relu<64><<<((size_t)N_NODES * 64 + 255) / 256, 256, 0, stream>>>(xw, dinv, b2, agg);

        hipMemsetAsync(gmax, 0, N_GRAPHS * sizeof(unsigned), stream);
        hipMemsetAsync(den, 0, N_GRAPHS * sizeof(float), stream);
        hipMemsetAsync(pooled, 0, N_GRAPHS * 64 * sizeof(float), stream);
        gate_kernel<<<NB, 256, 0, stream>>>(agg, gW1, gb1, gW2, gb2, batch, g, gmax);
        exp_kernel<<<NB, 256, 0, stream>>>(g, batch, gmax, ex, den);
        alpha_kernel<<<NB, 256, 0, stream>>>(ex, batch, den);
        int nchunks = (N_NODES + 31) / 32;
        pool_kernel<<<(nchunks + 3) / 4, 256, 0, stream>>>(agg, ex, batch, pooled);

        head_kernel<<<1, 256, 0, stream>>>(pooled, fcW1, fcb1, fcW2, fcb2, out);
    }
}

// Round 3
// 788.180 us; speedup vs baseline: 1.8461x; 1.0794x over previous
//
#include <hip/hip_runtime.h>
#include <hip/hip_bf16.h>

#define N_NODES 50000
#define N_EDGES 1600000
#define N_GRAPHS 64

// ---------- helpers ----------
__device__ __forceinline__ unsigned fenc(float x) {
    unsigned u = __float_as_uint(x);
    return (u & 0x80000000u) ? ~u : (u | 0x80000000u);
}
__device__ __forceinline__ float fdec(unsigned e) {
    return (e & 0x80000000u) ? __uint_as_float(e & 0x7fffffffu) : __uint_as_float(~e);
}

// ---------- GEMM: Y = X @ W, output in CHUNK-MAJOR layout [OUT/16][nrows][16] ----------
template<int IN, int OUT>
__global__ void gemm_rows_chunk(const float* __restrict__ X, const float* __restrict__ W,
                                float* __restrict__ Y, int nrows) {
    constexpr int NPB = 256 / OUT;                 // nodes per block-iteration
    __shared__ float Wl[IN * OUT];
    __shared__ float Xl[NPB * IN];
    for (int i = threadIdx.x; i < IN * OUT; i += 256) Wl[i] = W[i];
    __syncthreads();
    const int lane_out = threadIdx.x % OUT;
    const int lrow     = threadIdx.x / OUT;
    const size_t chunk_off = (size_t)(lane_out >> 4) * nrows * 16 + (lane_out & 15);
    for (int base = blockIdx.x * NPB; base < nrows; base += gridDim.x * NPB) {
        for (int i = threadIdx.x; i < NPB * IN; i += 256) {
            int r = base + i / IN;
            Xl[i] = (r < nrows) ? X[(size_t)r * IN + (i % IN)] : 0.f;
        }
        __syncthreads();
        int r = base + lrow;
        if (r < nrows) {
            float acc = 0.f;
            #pragma unroll 8
            for (int k = 0; k < IN; ++k)
                acc += Xl[lrow * IN + k] * Wl[k * OUT + lane_out];
            Y[chunk_off + (size_t)r * 16] = acc;
        }
        __syncthreads();
    }
}

// ---------- histogram: deg[dst] += ew (float), cnt[dst] += 1 (int) ----------
__global__ void hist_kernel(const int* __restrict__ dst, const float* __restrict__ ew,
                            float* __restrict__ deg, int* __restrict__ cnt) {
    int e = blockIdx.x * 256 + threadIdx.x;
    if (e < N_EDGES) {
        int d = dst[e];
        atomicAdd(&deg[d], ew[e]);
        atomicAdd(&cnt[d], 1);
    }
}

__global__ void dinv_kernel(float* __restrict__ deg_inplace) {
    int n = blockIdx.x * 256 + threadIdx.x;
    if (n < N_NODES) deg_inplace[n] = rsqrtf(deg_inplace[n] + 1.0f);
}

// ---------- prefix-scan (hierarchical, 3 kernels) ----------
__global__ void block_sums(const int* __restrict__ cnt, int* __restrict__ bsum) {
    __shared__ int s[256];
    int idx = blockIdx.x * 256 + threadIdx.x;
    s[threadIdx.x] = (idx < N_NODES) ? cnt[idx] : 0;
    __syncthreads();
    for (int o = 128; o; o >>= 1) {
        if (threadIdx.x < o) s[threadIdx.x] += s[threadIdx.x + o];
        __syncthreads();
    }
    if (threadIdx.x == 0) bsum[blockIdx.x] = s[0];
}

__global__ void scan_bsums(const int* __restrict__ bsum, int* __restrict__ boff,
                           int nb, int* __restrict__ row_start_last) {
    __shared__ int s[256];
    int v = (threadIdx.x < nb) ? bsum[threadIdx.x] : 0;
    s[threadIdx.x] = v;
    __syncthreads();
    for (int o = 1; o < 256; o <<= 1) {
        int t = 0;
        if (threadIdx.x >= o) t = s[threadIdx.x - o];
        __syncthreads();
        s[threadIdx.x] += t;
        __syncthreads();
    }
    if (threadIdx.x < nb) boff[threadIdx.x] = s[threadIdx.x] - v;   // exclusive
    if (threadIdx.x == 0) *row_start_last = N_EDGES;
}

__global__ void scan_counts(const int* __restrict__ cnt, const int* __restrict__ boff,
                            int* __restrict__ row_start, int* __restrict__ cursor) {
    __shared__ int s[256];
    int idx = blockIdx.x * 256 + threadIdx.x;
    int v = (idx < N_NODES) ? cnt[idx] : 0;
    s[threadIdx.x] = v;
    __syncthreads();
    for (int o = 1; o < 256; o <<= 1) {
        int t = 0;
        if (threadIdx.x >= o) t = s[threadIdx.x - o];
        __syncthreads();
        s[threadIdx.x] += t;
        __syncthreads();
    }
    if (idx < N_NODES) {
        int ex = boff[blockIdx.x] + s[threadIdx.x] - v;   // exclusive scan
        row_start[idx] = ex;
        cursor[idx]    = ex;
    }
}

// ---------- fill CSR: csr_src/csr_coef sorted by dst ----------
__global__ void fill_csr(const int* __restrict__ src, const int* __restrict__ dst,
                         const float* __restrict__ ew, const float* __restrict__ dinv,
                         int* __restrict__ cursor,
                         int* __restrict__ csr_src, float* __restrict__ csr_coef) {
    int e = blockIdx.x * 256 + threadIdx.x;
    if (e < N_EDGES) {
        int s = src[e], d = dst[e];
        float c = dinv[s] * ew[e] * dinv[d];
        int pos = atomicAdd(&cursor[d], 1);
        csr_src[pos]  = s;
        csr_coef[pos] = c;
    }
}

// ---------- CSR aggregation from chunk-major xw, XCD-L2-resident per chunk ----------
// xwc layout: [NC][N_NODES][16]; chunk = blockIdx.x % NC  (round-robin -> one chunk per XCD,
// 3.2 MB slice fits the 4 MB per-XCD L2). Output written row-major, fused selfloop+bias+relu.
template<int NC>
__global__ void agg_csr_chunk(const int* __restrict__ row_start, const int* __restrict__ csr_src,
                              const float* __restrict__ csr_coef, const float* __restrict__ xwc,
                              const float* __restrict__ dinv, const float* __restrict__ b,
                              float* __restrict__ out_h) {
    constexpr int OUT = NC * 16;
    const int c  = blockIdx.x % NC;
    const int nb = blockIdx.x / NC;
    const int n  = nb * 16 + (threadIdx.x >> 4);
    const int kk = threadIdx.x & 15;
    if (n >= N_NODES) return;
    const float* __restrict__ base = xwc + (size_t)c * N_NODES * 16 + kk;
    const int beg = row_start[n], end = row_start[n + 1];
    float acc = 0.f;
    int i = beg;
    for (; i + 3 < end; i += 4) {
        int s0 = csr_src[i],     s1 = csr_src[i + 1];
        int s2 = csr_src[i + 2], s3 = csr_src[i + 3];
        float c0 = csr_coef[i],     c1 = csr_coef[i + 1];
        float c2 = csr_coef[i + 2], c3 = csr_coef[i + 3];
        acc += c0 * base[(size_t)s0 * 16] + c1 * base[(size_t)s1 * 16]
             + c2 * base[(size_t)s2 * 16] + c3 * base[(size_t)s3 * 16];
    }
    for (; i < end; ++i) acc += csr_coef[i] * base[(size_t)csr_src[i] * 16];
    float di = dinv[n];
    int kg = c * 16 + kk;
    float v = acc + di * di * base[(size_t)n * 16] + b[kg];
    out_h[(size_t)n * OUT + kg] = fmaxf(v, 0.f);
}

// ---------- gate: g[n] = relu(x1@gW1+gb1)@gW2+gb2; wave-reduced segment max ----------
__global__ void gate_kernel(const float* __restrict__ x1, const float* __restrict__ gW1,
                            const float* __restrict__ gb1, const float* __restrict__ gW2,
                            const float* __restrict__ gb2, const int* __restrict__ batch,
                            float* __restrict__ g, unsigned* __restrict__ gmax_enc) {
    __shared__ float W1l[64 * 32];
    __shared__ float W2l[32];
    __shared__ float b1l[32];
    for (int i = threadIdx.x; i < 64 * 32; i += 256) W1l[i] = gW1[i];
    if (threadIdx.x < 32) { W2l[threadIdx.x] = gW2[threadIdx.x]; b1l[threadIdx.x] = gb1[threadIdx.x]; }
    __syncthreads();
    const float gb2v = gb2[0];
    int n = blockIdx.x * 256 + threadIdx.x;
    bool act = (n < N_NODES);
    float gv = -1e30f;
    int b = 0;
    if (act) {
        const float* row = x1 + (size_t)n * 64;
        float t[32];
        #pragma unroll
        for (int j = 0; j < 32; ++j) t[j] = b1l[j];
        for (int k = 0; k < 64; ++k) {
            float xv = row[k];
            #pragma unroll
            for (int j = 0; j < 32; ++j) t[j] += xv * W1l[k * 32 + j];
        }
        float a = gb2v;
        #pragma unroll
        for (int j = 0; j < 32; ++j) a += fmaxf(t[j], 0.f) * W2l[j];
        gv = a;
        g[n] = a;
        b = batch[n];
    }
    unsigned long long actm = __ballot(act);
    int b0 = __shfl(b, 0);
    bool uniform = (actm == ~0ull) && (__ballot(b == b0) == ~0ull);
    if (uniform) {
        float m = gv;
        for (int o = 32; o; o >>= 1) m = fmaxf(m, __shfl_xor(m, o));
        if ((threadIdx.x & 63) == 0) atomicMax(&gmax_enc[b0], fenc(m));
    } else if (act) {
        atomicMax(&gmax_enc[b], fenc(gv));
    }
}

__global__ void exp_kernel(const float* __restrict__ g, const int* __restrict__ batch,
                           const unsigned* __restrict__ gmax_enc, float* __restrict__ ex,
                           float* __restrict__ den) {
    int n = blockIdx.x * 256 + threadIdx.x;
    bool act = (n < N_NODES);
    float v = 0.f; int b = 0;
    if (act) {
        b = batch[n];
        v = expf(g[n] - fdec(gmax_enc[b]));
        ex[n] = v;
    }
    unsigned long long actm = __ballot(act);
    int b0 = __shfl(b, 0);
    bool uniform = (actm == ~0ull) && (__ballot(b == b0) == ~0ull);
    if (uniform) {
        float s = v;
        for (int o = 32; o; o >>= 1) s += __shfl_xor(s, o);
        if ((threadIdx.x & 63) == 0) atomicAdd(&den[b0], s);
    } else if (act) {
        atomicAdd(&den[b], v);
    }
}

__global__ void alpha_kernel(float* __restrict__ ex, const int* __restrict__ batch,
                             const float* __restrict__ den) {
    int n = blockIdx.x * 256 + threadIdx.x;
    if (n < N_NODES) ex[n] = ex[n] / den[batch[n]];
}

// ---------- pooled[batch] += alpha * x1 (run-length accumulate, batch sorted) ----------
__global__ void pool_kernel(const float* __restrict__ x1, const float* __restrict__ alpha,
                            const int* __restrict__ batch, float* __restrict__ pooled) {
    const int L = 32;
    const int f   = threadIdx.x & 63;
    const int grp = threadIdx.x >> 6;
    int chunk = blockIdx.x * 4 + grp;
    int start = chunk * L;
    if (start >= N_NODES) return;
    int end = min(start + L, N_NODES);
    int cur = batch[start];
    float acc = 0.f;
    for (int n = start; n < end; ++n) {
        int bb = batch[n];
        if (bb != cur) { atomicAdd(&pooled[cur * 64 + f], acc); acc = 0.f; cur = bb; }
        acc += alpha[n] * x1[(size_t)n * 64 + f];
    }
    atomicAdd(&pooled[cur * 64 + f], acc);
}

// ---------- head ----------
__global__ void head_kernel(const float* __restrict__ pooled, const float* __restrict__ fcW1,
                            const float* __restrict__ fcb1, const float* __restrict__ fcW2,
                            const float* __restrict__ fcb2, float* __restrict__ out) {
    __shared__ float P[64 * 64];
    __shared__ float W1l[64 * 128];
    __shared__ float H[64 * 128];
    for (int i = threadIdx.x; i < 64 * 64; i += 256) P[i] = pooled[i];
    for (int i = threadIdx.x; i < 64 * 128; i += 256) W1l[i] = fcW1[i];
    __syncthreads();
    for (int i = threadIdx.x; i < 64 * 128; i += 256) {
        int gi = i >> 7, j = i & 127;
        float a = fcb1[j];
        for (int k = 0; k < 64; ++k) a += P[gi * 64 + k] * W1l[k * 128 + j];
        H[i] = fmaxf(a, 0.f);
    }
    __syncthreads();
    if (threadIdx.x < 64) {
        int gi = threadIdx.x;
        float l0 = fcb2[0], l1 = fcb2[1];
        for (int k = 0; k < 128; ++k) {
            float h = H[gi * 128 + k];
            l0 += h * fcW2[k * 2 + 0];
            l1 += h * fcW2[k * 2 + 1];
        }
        float m = fmaxf(l0, l1);
        float lse = m + logf(expf(l0 - m) + expf(l1 - m));
        out[gi * 2 + 0] = l0 - lse;
        out[gi * 2 + 1] = l1 - lse;
    }
}

extern "C" void kernel_launch(void* const* d_in, const int* in_sizes, int n_in,
                              void* d_out, int out_size, void* d_ws, size_t ws_size,
                              hipStream_t stream) {
    const float* x    = (const float*)d_in[0];
    const int*   ei   = (const int*)d_in[1];
    const float* ew   = (const float*)d_in[2];
    const int*   batch= (const int*)d_in[3];
    const float* W1   = (const float*)d_in[4];
    const float* b1   = (const float*)d_in[5];
    const float* W2   = (const float*)d_in[6];
    const float* b2   = (const float*)d_in[7];
    const float* gW1  = (const float*)d_in[8];
    const float* gb1  = (const float*)d_in[9];
    const float* gW2  = (const float*)d_in[10];
    const float* gb2  = (const float*)d_in[11];
    const float* fcW1 = (const float*)d_in[12];
    const float* fcb1 = (const float*)d_in[13];
    const float* fcW2 = (const float*)d_in[14];
    const float* fcb2 = (const float*)d_in[15];
    float* out = (float*)d_out;

    const int* src = ei;
    const int* dst = ei + N_EDGES;

    const int EB = (N_EDGES + 255) / 256;    // 6250
    const int NB = (N_NODES + 255) / 256;    // 196
    const int NBLK16 = (N_NODES + 15) / 16;  // 3125 node-blocks of 16

    // ---- workspace layout (floats) ----
    float* ws = (float*)d_ws;
    float* xw    = ws;                        // 6,400,000 (chunk-major [NC][N][16])
    float* agg   = ws + 6400000;              // 6,400,000 (row-major h / x1)
    size_t off = 12800000;
    int*   csr_src  = (int*)(ws + off);   off += 1600000;
    float* csr_coef = ws + off;           off += 1600000;
    int*   row_start= (int*)(ws + off);   off += 50048;
    int*   cnt      = (int*)(ws + off);   off += 50048;
    int*   cursor   = (int*)(ws + off);   off += 50048;
    float* dinv     = ws + off;           off += 50048;
    float* g        = ws + off;           off += 50048;
    float* ex       = ws + off;           off += 50048;
    int*   bsum     = (int*)(ws + off);   off += 256;
    int*   boff     = (int*)(ws + off);   off += 256;
    unsigned* gmax  = (unsigned*)(ws + off); off += 64;
    float* den      = ws + off;           off += 64;
    float* pooled   = ws + off;           off += 4096;

    // degrees + counts
    hipMemsetAsync(dinv, 0, N_NODES * sizeof(float), stream);
    hipMemsetAsync(cnt, 0, N_NODES * sizeof(int), stream);
    hist_kernel<<<EB, 256, 0, stream>>>(dst, ew, dinv, cnt);
    dinv_kernel<<<NB, 256, 0, stream>>>(dinv);

    // prefix scan -> row_start, cursor
    block_sums<<<NB, 256, 0, stream>>>(cnt, bsum);
    scan_bsums<<<1, 256, 0, stream>>>(bsum, boff, NB, row_start + N_NODES);
    scan_counts<<<NB, 256, 0, stream>>>(cnt, boff, row_start, cursor);

    // fill CSR (coef computed inline)
    fill_csr<<<EB, 256, 0, stream>>>(src, dst, ew, dinv, cursor, csr_src, csr_coef);

    // conv1: xw1 = x@W1 (chunk-major, NC=8); agg fused selfloop+bias+relu -> h (row-major)
    gemm_rows_chunk<128, 128><<<2048, 256, 0, stream>>>(x, W1, xw, N_NODES);
    agg_csr_chunk<8><<<8 * NBLK16, 256, 0, stream>>>(row_start, csr_src, csr_coef,
                                                     xw, dinv, b1, agg);

    // conv2: xw2 = h@W2 (chunk-major, NC=4); agg -> x1 (row-major)
    gemm_rows_chunk<128, 64><<<2048, 256, 0, stream>>>(agg, W2, xw, N_NODES);
    agg_csr_chunk<4><<<4 * NBLK16, 256, 0, stream>>>(row_start, csr_src, csr_coef,
                                                     xw, dinv, b2, agg);

    // global attention
    hipMemsetAsync(gmax, 0, N_GRAPHS * sizeof(unsigned), stream);
    hipMemsetAsync(den, 0, N_GRAPHS * sizeof(float), stream);
    hipMemsetAsync(pooled, 0, N_GRAPHS * 64 * sizeof(float), stream);
    gate_kernel<<<NB, 256, 0, stream>>>(agg, gW1, gb1, gW2, gb2, batch, g, gmax);
    exp_kernel<<<NB, 256, 0, stream>>>(g, batch, gmax, ex, den);
    alpha_kernel<<<NB, 256, 0, stream>>>(ex, batch, den);
    int nchunks = (N_NODES + 31) / 32;
    pool_kernel<<<(nchunks + 3) / 4, 256, 0, stream>>>(agg, ex, batch, pooled);

    // head
    head_kernel<<<1, 256, 0, stream>>>(pooled, fcW1, fcb1, fcW2, fcb2, out);
}